// Round 19
// baseline (19.694 us; speedup 1.0000x reference)
//
#include <hip/hip_runtime.h>

#define B 16
#define CIN 4
#define COUT 8
#define KW 5
#define S 2048
#define BS (B * S)

typedef _Float16 f16;
typedef _Float16 f16x4 __attribute__((ext_vector_type(4)));
typedef _Float16 f16x8 __attribute__((ext_vector_type(8)));
typedef __fp16 fp16x2 __attribute__((ext_vector_type(2)));
typedef float f32x16 __attribute__((ext_vector_type(16)));

// V^T fragment ordering within a 32-kv tile (A-operand of PV MFMA):
__device__ __forceinline__ int vfrag_off(int k) {
    return (((k >> 2) & 1) << 4) | (((k >> 4) & 1) << 3) | (k & 3) | (((k >> 3) & 1) << 2);
}

// ---------------------------------------------------------------------------
// Kernel 1: three causal (reflect-padded) convs (R17 verbatim, XCD co-located:
// batch b's blocks on XCD b&7, matching attn's swizzle).
// part 0: qe = conv(q, wq) * QSCALE -> [b][s][8] f16   (exp2-domain scale)
// part 1: ke = conv(v, wk)          -> [b][s][8] f16   (swapped wiring!)
// part 2: ve = conv(k, wv)          -> vt2 [b][tile][n][frag-order] f16,
//          row n=8 = 1.0 (ones row -> softmax denominator via PV MFMA).
// ---------------------------------------------------------------------------
__global__ __launch_bounds__(256) void conv_embed_kernel(
    const float* __restrict__ q, const float* __restrict__ k,
    const float* __restrict__ v, const float* __restrict__ wq,
    const float* __restrict__ wk, const float* __restrict__ wv,
    f16* __restrict__ qe, f16* __restrict__ ke, f16* __restrict__ vt2)
{
    __shared__ float wsm[80];

    int tid  = threadIdx.x;
    int bid  = blockIdx.x;
    int xcd  = bid & 7;
    int slot = bid >> 3;           // 0..95
    int grp  = slot >> 4;          // 0..5
    int r    = slot & 15;
    int b    = xcd + ((r >> 3) << 3);   // batches {xcd, xcd+8}
    int chunk= r & 7;
    int part = grp >> 1;           // 0,1,2
    int oh   = grp & 1;            // oc half

    const float* in; const float* wsrc;
    if (part == 0)      { in = q; wsrc = wq; }
    else if (part == 1) { in = v; wsrc = wk; }   // ke = conv(v, wk)
    else                { in = k; wsrc = wv; }   // ve = conv(k, wv)

    if (tid < 80) wsm[tid] = wsrc[oh * 80 + tid];
    __syncthreads();

    int s = chunk * 256 + tid;
    int gid = b * S + s;

    float x[CIN][KW];
#pragma unroll
    for (int c = 0; c < CIN; ++c) {
        const float* ip = in + ((size_t)(b * CIN + c) << 11);
#pragma unroll
        for (int i = 0; i < KW; ++i) {
            int idx = s + i - 4;
            idx = idx < 0 ? -idx : idx;   // reflect pad
            x[c][i] = ip[idx];
        }
    }

    float o[4];
#pragma unroll
    for (int oo = 0; oo < 4; ++oo) {
        float a = 0.f;
#pragma unroll
        for (int c = 0; c < CIN; ++c)
#pragma unroll
            for (int i = 0; i < KW; ++i)
                a += x[c][i] * wsm[oo * 20 + c * 5 + i];
        o[oo] = a;
    }

    const float QSCALE = 0.35355339059327373f * 1.4426950408889634f; // (1/sqrt8)*log2e

    if (part == 2) {
        int t   = s >> 5;
        int off = vfrag_off(s & 31);
        size_t base = (size_t)(b * 64 + t) * 9;
#pragma unroll
        for (int oo = 0; oo < 4; ++oo)
            vt2[((base + oh * 4 + oo) << 5) + off] = (f16)o[oo];
        if (oh == 0)                                   // ones row (n = 8)
            vt2[((base + 8) << 5) + off] = (f16)1.0f;
    } else {
        float sc = (part == 0) ? QSCALE : 1.0f;
        f16x4 r4;
#pragma unroll
        for (int oo = 0; oo < 4; ++oo) r4[oo] = (f16)(o[oo] * sc);
        f16* dst = ((part == 0) ? qe : ke) + ((size_t)gid << 3) + oh * 4;
        *(f16x4*)dst = r4;
    }
}

// ---------------------------------------------------------------------------
// Kernel 2: flash attention, R18 structure with the swizzle-collision fix.
// Grid 512 x 512thr (2 blocks/CU). Block owns 2 q-tiles of one batch.
// K/V staged into LDS in TWO half-batch phases; bulk coalesced 16B loads =
// max MLP for cold misses; inner loop reads LDS; each tile feeds BOTH q-tiles.
//
// LDS swizzles (write & read identical formulas — rule #21):
//   K: f16 off = kv*8 ^ (bit3(kv)<<3)          (granule-LSB XOR, injective)
//   V: TILE STRIDE 320 (mult of 64! — 288 caused odd-tile bit-5 carry to
//      collide with the XOR: (288+96)^16 == (288+144)^32 == 400) then
//      off = (t*320 + row*32 + g*8) ^ (((row>>1)&3)<<4)  — injective, <=2-way.
// Fragment math identical to R14/R17 (split-k, swapped QK^T, ones-row
// denominator, row-clamped V for lanes 9..31).
// ---------------------------------------------------------------------------
#define QT 32
#define NWAVE 8

#if __has_builtin(__builtin_amdgcn_mfma_f32_32x32x8f16)
#define HAVE_K8 1
#else
#define HAVE_K8 0
#endif

__global__ __launch_bounds__(512, 2) void attn_mfma_kernel(
    const f16* __restrict__ qe, const f16* __restrict__ ke,
    const f16* __restrict__ vt2, const float* __restrict__ w_out,
    const float* __restrict__ b_out, float* __restrict__ out)
{
    __shared__ f16 kls[1024 * 8];        // 16 KB: half-batch K (swizzled)
    __shared__ f16 vls[32 * 320];        // 20 KB: half-batch V (PADDED stride)
    __shared__ float red[NWAVE][9][QT];  // 9 KB

    int tid  = threadIdx.x;
    int w    = tid >> 6;
    int lane = tid & 63;
    int hi   = lane >> 5;
    int ln   = lane & 31;

    // XCD co-location: 512 = 8 xcd x 64 slots; batch b on XCD b&7.
    int bid  = blockIdx.x;
    int xcd  = bid & 7;
    int slot = bid >> 3;                 // 0..63
    int b    = xcd + ((slot >> 5) << 3); // batches {xcd, xcd+8}
    int blks = slot & 31;                // 0..31 -> q-tiles 2*blks..2*blks+1

    // Q fragments for both q-tiles (B operand): elems 0..3 = Q[q0+ln][4hi..]
    f16x4 qb[2];
#pragma unroll
    for (int qt = 0; qt < 2; ++qt) {
        int q0 = (blks * 2 + qt) * QT;
        qb[qt] = *(const f16x4*)(qe + ((size_t)(b * S + q0 + ln) << 3) + hi * 4);
    }
#if !HAVE_K8
    f16x8 qb8[2];
#pragma unroll
    for (int qt = 0; qt < 2; ++qt)
        qb8[qt] = (f16x8){qb[qt][0], qb[qt][1], qb[qt][2], qb[qt][3],
                          (f16)0, (f16)0, (f16)0, (f16)0};
#endif

    const f32x16 zero16 = {};
    f32x16 oacc0 = {}, oacc1 = {};       // one per q-tile; row n=8 = l

    int vrow = ln < 9 ? ln : 8;          // row-clamp (lanes 9..31 don't-care)

#pragma unroll
    for (int h = 0; h < 2; ++h) {
        __syncthreads();                 // prior phase's reads done
        // ---- stage K half (1024 kv x 16B), swizzled ----
        for (int u = tid; u < 1024; u += 512) {
            *(f16x8*)&kls[(u * 8) ^ (((u >> 3) & 1) << 3)] =
                *(const f16x8*)(ke + ((size_t)(b * S + h * 1024 + u) << 3));
        }
        // ---- stage V half (32 tiles x 9 rows x 64B), stride 320, swizzled ----
        for (int u = tid; u < 1152; u += 512) {
            int t = u / 36, r2 = u % 36, row = r2 >> 2, q4 = r2 & 3;
            *(f16x8*)&vls[(t * 320 + row * 32 + q4 * 8) ^ (((row >> 1) & 3) << 4)] =
                *(const f16x8*)(vt2 + ((((size_t)(b * 64 + h * 32 + t) * 9 + row) << 5) + q4 * 8));
        }
        __syncthreads();                 // staging visible

#pragma unroll
        for (int it = 0; it < 4; ++it) {
            int kvl = w * 128 + it * 32 + ln;
            f16x4 kh = *(const f16x4*)&kls[((kvl * 8) ^ (((kvl >> 3) & 1) << 3)) + hi * 4];
            int tl = w * 4 + it;
            int voff = (tl * 320 + vrow * 32 + hi * 16) ^ (((vrow >> 1) & 3) << 4);
            f16x8 va1 = *(const f16x8*)&vls[voff];
            f16x8 va2 = *(const f16x8*)&vls[voff + 8];

#pragma unroll
            for (int qt = 0; qt < 2; ++qt) {
#if HAVE_K8
                f32x16 sc = __builtin_amdgcn_mfma_f32_32x32x8f16(kh, qb[qt], zero16, 0, 0, 0);
#else
                f16x8 ka = {kh[0], kh[1], kh[2], kh[3], (f16)0, (f16)0, (f16)0, (f16)0};
                f32x16 sc = __builtin_amdgcn_mfma_f32_32x32x16_f16(ka, qb8[qt], zero16, 0, 0, 0);
#endif
                union { f16x8 v; fp16x2 h2[4]; } p1, p2;
#pragma unroll
                for (int i = 0; i < 4; ++i) {
                    p1.h2[i] = __builtin_amdgcn_cvt_pkrtz(__builtin_amdgcn_exp2f(sc[2 * i]),
                                                          __builtin_amdgcn_exp2f(sc[2 * i + 1]));
                    p2.h2[i] = __builtin_amdgcn_cvt_pkrtz(__builtin_amdgcn_exp2f(sc[8 + 2 * i]),
                                                          __builtin_amdgcn_exp2f(sc[8 + 2 * i + 1]));
                }
                if (qt == 0) {
                    oacc0 = __builtin_amdgcn_mfma_f32_32x32x16_f16(va1, p1.v, oacc0, 0, 0, 0);
                    oacc0 = __builtin_amdgcn_mfma_f32_32x32x16_f16(va2, p2.v, oacc0, 0, 0, 0);
                } else {
                    oacc1 = __builtin_amdgcn_mfma_f32_32x32x16_f16(va1, p1.v, oacc1, 0, 0, 0);
                    oacc1 = __builtin_amdgcn_mfma_f32_32x32x16_f16(va2, p2.v, oacc1, 0, 0, 0);
                }
            }
        }
    }

    // ---- epilogues: one per q-tile ----
#pragma unroll
    for (int qt = 0; qt < 2; ++qt) {
        f32x16 oacc = (qt == 0) ? oacc0 : oacc1;
        __syncthreads();                 // protect red[] reuse
#pragma unroll
        for (int r = 0; r < 16; ++r) {
            int n = (r & 3) + 8 * (r >> 2) + 4 * hi;
            if (n < 9) red[w][n][ln] = oacc[r];
        }
        __syncthreads();

        if (tid < 9 * QT) {
            int n = tid >> 5, qq = tid & 31;
            float a = red[0][n][qq];
#pragma unroll
            for (int ww = 1; ww < NWAVE; ++ww) a += red[ww][n][qq];
            red[0][n][qq] = a;
        }
        __syncthreads();

        if (tid < 256) {
            int cp = tid >> 5, qq = tid & 31;
            int q0 = (blks * 2 + qt) * QT;
            float inv = 1.0f / red[0][8][qq];
            float y = b_out[cp];
#pragma unroll
            for (int c = 0; c < 8; ++c) y += w_out[cp * 8 + c] * red[0][c][qq] * inv;
            out[(((size_t)(b * COUT + cp)) << 11) + q0 + qq] = y;
        }
    }
}

// ---------------------------------------------------------------------------
extern "C" void kernel_launch(void* const* d_in, const int* in_sizes, int n_in,
                              void* d_out, int out_size, void* d_ws, size_t ws_size,
                              hipStream_t stream)
{
    const float* q     = (const float*)d_in[0];
    const float* k     = (const float*)d_in[1];
    const float* v     = (const float*)d_in[2];
    const float* wq    = (const float*)d_in[3];
    const float* wk    = (const float*)d_in[4];
    const float* wv    = (const float*)d_in[5];
    const float* w_out = (const float*)d_in[6];
    const float* b_out = (const float*)d_in[7];
    float* out = (float*)d_out;

    f16* qe  = (f16*)d_ws;                       // [B][S][8]
    f16* ke  = qe + (size_t)BS * COUT;           // [B][S][8]
    f16* vt2 = ke + (size_t)BS * COUT;           // [B][64][9][32] frag-ordered

    conv_embed_kernel<<<768, 256, 0, stream>>>(q, k, v, wq, wk, wv, qe, ke, vt2);
    attn_mfma_kernel<<<512, 512, 0, stream>>>(qe, ke, vt2, w_out, b_out, out);
}

// Round 20
// 18.448 us; speedup vs baseline: 1.0675x; 1.0675x over previous
//
#include <hip/hip_runtime.h>

#define B 16
#define CIN 4
#define COUT 8
#define KW 5
#define S 2048
#define BS (B * S)

typedef _Float16 f16;
typedef _Float16 f16x4 __attribute__((ext_vector_type(4)));
typedef _Float16 f16x8 __attribute__((ext_vector_type(8)));
typedef __fp16 fp16x2 __attribute__((ext_vector_type(2)));
typedef float f32x16 __attribute__((ext_vector_type(16)));

// V^T fragment ordering within a 32-kv tile (A-operand of PV MFMA):
__device__ __forceinline__ int vfrag_off(int k) {
    return (((k >> 2) & 1) << 4) | (((k >> 4) & 1) << 3) | (k & 3) | (((k >> 3) & 1) << 2);
}

// ---------------------------------------------------------------------------
// Kernel 1: three causal (reflect-padded) convs. XCD co-located: batch b's
// blocks on XCD b&7 (matches attn's swizzle) so conv's written-back lines
// stay resident in the L2 the readers run on.
// part 0: qe = conv(q, wq) * QSCALE -> [b][s][8] f16   (exp2-domain scale)
// part 1: ke = conv(v, wk)          -> [b][s][8] f16   (swapped wiring!)
// part 2: ve = conv(k, wv)          -> vt2 [b][tile][n][frag-order] f16,
//          row n=8 = 1.0 (ones row -> softmax denominator via PV MFMA).
// ---------------------------------------------------------------------------
__global__ __launch_bounds__(256) void conv_embed_kernel(
    const float* __restrict__ q, const float* __restrict__ k,
    const float* __restrict__ v, const float* __restrict__ wq,
    const float* __restrict__ wk, const float* __restrict__ wv,
    f16* __restrict__ qe, f16* __restrict__ ke, f16* __restrict__ vt2)
{
    __shared__ float wsm[80];

    int tid  = threadIdx.x;
    // XCD co-location swizzle (bijective over 768 = 8 xcd x 96 slots):
    int bid  = blockIdx.x;
    int xcd  = bid & 7;
    int slot = bid >> 3;           // 0..95
    int grp  = slot >> 4;          // 0..5
    int r    = slot & 15;
    int b    = xcd + ((r >> 3) << 3);   // batches {xcd, xcd+8}
    int chunk= r & 7;              // position chunk within batch
    int part = grp >> 1;           // 0,1,2
    int oh   = grp & 1;            // oc half

    const float* in; const float* wsrc;
    if (part == 0)      { in = q; wsrc = wq; }
    else if (part == 1) { in = v; wsrc = wk; }   // ke = conv(v, wk)
    else                { in = k; wsrc = wv; }   // ve = conv(k, wv)

    if (tid < 80) wsm[tid] = wsrc[oh * 80 + tid];
    __syncthreads();

    int s = chunk * 256 + tid;
    int gid = b * S + s;

    float x[CIN][KW];
#pragma unroll
    for (int c = 0; c < CIN; ++c) {
        const float* ip = in + ((size_t)(b * CIN + c) << 11);
#pragma unroll
        for (int i = 0; i < KW; ++i) {
            int idx = s + i - 4;
            idx = idx < 0 ? -idx : idx;   // reflect pad
            x[c][i] = ip[idx];
        }
    }

    float o[4];
#pragma unroll
    for (int oo = 0; oo < 4; ++oo) {
        float a = 0.f;
#pragma unroll
        for (int c = 0; c < CIN; ++c)
#pragma unroll
            for (int i = 0; i < KW; ++i)
                a += x[c][i] * wsm[oo * 20 + c * 5 + i];
        o[oo] = a;
    }

    const float QSCALE = 0.35355339059327373f * 1.4426950408889634f; // (1/sqrt8)*log2e

    if (part == 2) {
        int t   = s >> 5;
        int off = vfrag_off(s & 31);
        size_t base = (size_t)(b * 64 + t) * 9;
#pragma unroll
        for (int oo = 0; oo < 4; ++oo)
            vt2[((base + oh * 4 + oo) << 5) + off] = (f16)o[oo];
        if (oh == 0)                                   // ones row (n = 8)
            vt2[((base + 8) << 5) + off] = (f16)1.0f;
    } else {
        float sc = (part == 0) ? QSCALE : 1.0f;
        f16x4 r4;
#pragma unroll
        for (int oo = 0; oo < 4; ++oo) r4[oo] = (f16)(o[oo] * sc);
        f16* dst = ((part == 0) ? qe : ke) + ((size_t)gid << 3) + oh * 4;
        *(f16x4*)dst = r4;
    }
}

// ---------------------------------------------------------------------------
// Kernel 2: flash attention (best-measured configuration, R17/R14 lineage).
// XCD co-location: all 64 q-tile blocks of batch b on XCD b&7.
//
// SPLIT-K fragment layout:
//   32x32x8  A/B: lane l elem j <-> k = (l>>5)*4 + j
//   C/D: col = lane&31, row = (r&3) + 8*(r>>2) + 4*(lane>>5)
// QK^T swapped: C[kv][q] = mfma(A=K, B=Q^T); p = exp2(C) feeds PV's B
// fragment DIRECTLY. PV: C[n][q] += mfma(A=V^T, B=P) x2; row n==8 (ones row
// in vt2) accumulates denominator l. Lanes 9..31: row-clamped V pointer
// (their C rows are never read).
// ---------------------------------------------------------------------------
#define QT 32
#define NWAVE 8
#define KVC (S / NWAVE)   // 256 kv per wave

#if __has_builtin(__builtin_amdgcn_mfma_f32_32x32x8f16)
#define HAVE_K8 1
#else
#define HAVE_K8 0
#endif

__global__ __launch_bounds__(512, 4) void attn_mfma_kernel(
    const f16* __restrict__ qe, const f16* __restrict__ ke,
    const f16* __restrict__ vt2, const float* __restrict__ w_out,
    const float* __restrict__ b_out, float* __restrict__ out)
{
    __shared__ float red[NWAVE][9][QT];

    int tid  = threadIdx.x;
    int w    = tid >> 6;
    int lane = tid & 63;
    int hi   = lane >> 5;
    int ln   = lane & 31;

    // XCD co-location swizzle (bijective over 1024 = 8 xcd x 128 slots):
    int bid  = blockIdx.x;
    int xcd  = bid & 7;
    int slot = bid >> 3;           // 0..127
    int b    = xcd + ((slot >> 6) << 3);   // batches {xcd, xcd+8}
    int q0   = (slot & 63) * QT;

    // Q fragment (B operand): elems 0..3 = Q[q0+ln][4*hi..4*hi+3]
    f16x4 qb4 = *(const f16x4*)(qe + ((size_t)(b * S + q0 + ln) << 3) + hi * 4);
#if !HAVE_K8
    f16x8 qb8 = {qb4[0], qb4[1], qb4[2], qb4[3], (f16)0, (f16)0, (f16)0, (f16)0};
#endif

    const f32x16 zero16 = {};
    f32x16 oacc = {};              // C[n][q]; row n=8 accumulates l

    int vrow = ln < 9 ? ln : 8;    // row-clamp: lanes 9..31 -> row 8 (don't-care)
    const f16* kptr = ke + ((size_t)(b * S + w * KVC + ln) << 3) + hi * 4;
    const f16* vptr = vt2 + (((size_t)(b * 64 + w * (KVC / 32)) * 9 + vrow) << 5) + hi * 16;

#pragma unroll
    for (int it = 0; it < KVC / 32; ++it) {
        // ---- QK^T (C-in = persistent zero) ----
        f16x4 kh = *(const f16x4*)kptr;
        kptr += 32 * 8;
#if HAVE_K8
        f32x16 sc = __builtin_amdgcn_mfma_f32_32x32x8f16(kh, qb4, zero16, 0, 0, 0);
#else
        f16x8 ka = {kh[0], kh[1], kh[2], kh[3], (f16)0, (f16)0, (f16)0, (f16)0};
        f32x16 sc = __builtin_amdgcn_mfma_f32_32x32x16_f16(ka, qb8, zero16, 0, 0, 0);
#endif

        // ---- exp2 fused into f16 pack (owned C-rows == needed B-frag k) ----
        union { f16x8 v; fp16x2 h[4]; } p1, p2;
#pragma unroll
        for (int i = 0; i < 4; ++i) {
            p1.h[i] = __builtin_amdgcn_cvt_pkrtz(__builtin_amdgcn_exp2f(sc[2 * i]),
                                                 __builtin_amdgcn_exp2f(sc[2 * i + 1]));
            p2.h[i] = __builtin_amdgcn_cvt_pkrtz(__builtin_amdgcn_exp2f(sc[8 + 2 * i]),
                                                 __builtin_amdgcn_exp2f(sc[8 + 2 * i + 1]));
        }

        // ---- V^T A-fragments: unconditional row-clamped loads ----
        f16x8 va1 = *(const f16x8*)(vptr);
        f16x8 va2 = *(const f16x8*)(vptr + 8);
        vptr += 9 * 32;

        oacc = __builtin_amdgcn_mfma_f32_32x32x16_f16(va1, p1.v, oacc, 0, 0, 0);
        oacc = __builtin_amdgcn_mfma_f32_32x32x16_f16(va2, p2.v, oacc, 0, 0, 0);
    }

    // ---- epilogue: dump useful C rows (n<9) to LDS ----
#pragma unroll
    for (int r = 0; r < 16; ++r) {
        int n = (r & 3) + 8 * (r >> 2) + 4 * hi;
        if (n < 9) red[w][n][ln] = oacc[r];
    }
    __syncthreads();

    // Reduce the 8 kv-chunk waves: 9 rows x 32 q = 288 items (512 threads).
    if (tid < 9 * QT) {
        int n = tid >> 5, qq = tid & 31;
        float a = red[0][n][qq];
#pragma unroll
        for (int ww = 1; ww < NWAVE; ++ww) a += red[ww][n][qq];
        red[0][n][qq] = a;
    }
    __syncthreads();

    if (tid < 256) {
        int cp = tid >> 5, qq = tid & 31;   // 8 channels x 32 q
        float inv = 1.0f / red[0][8][qq];
        float y = b_out[cp];
#pragma unroll
        for (int c = 0; c < 8; ++c) y += w_out[cp * 8 + c] * red[0][c][qq] * inv;
        out[(((size_t)(b * COUT + cp)) << 11) + q0 + qq] = y;
    }
}

// ---------------------------------------------------------------------------
extern "C" void kernel_launch(void* const* d_in, const int* in_sizes, int n_in,
                              void* d_out, int out_size, void* d_ws, size_t ws_size,
                              hipStream_t stream)
{
    const float* q     = (const float*)d_in[0];
    const float* k     = (const float*)d_in[1];
    const float* v     = (const float*)d_in[2];
    const float* wq    = (const float*)d_in[3];
    const float* wk    = (const float*)d_in[4];
    const float* wv    = (const float*)d_in[5];
    const float* w_out = (const float*)d_in[6];
    const float* b_out = (const float*)d_in[7];
    float* out = (float*)d_out;

    f16* qe  = (f16*)d_ws;                       // [B][S][8]
    f16* ke  = qe + (size_t)BS * COUT;           // [B][S][8]
    f16* vt2 = ke + (size_t)BS * COUT;           // [B][64][9][32] frag-ordered

    conv_embed_kernel<<<768, 256, 0, stream>>>(q, k, v, wq, wk, wv, qe, ke, vt2);
    attn_mfma_kernel<<<B * (S / QT), 512, 0, stream>>>(qe, ke, vt2, w_out, b_out, out);
}